// Round 11
// baseline (101.854 us; speedup 1.0000x reference)
//
#include <hip/hip_runtime.h>
#include <math.h>

namespace {
constexpr int B = 32, C = 2, T = 262144, K = 6;
constexpr int SEG = 1024;         // segments per (b,c)
constexpr int L = T / SEG;        // 256 samples per segment
constexpr int NBC = B * C;        // 64 sequences
constexpr int NST = 2 * K;        // 12-dim cascade state
constexpr int LOG2L = 8;          // L = 2^8
constexpr int GP = SEG / 64;      // 16 segments per scan lane
constexpr int TS = 16;            // samples per staging tile
constexpr int NT = L / TS;        // 16 tiles
constexpr int WPB = SEG / 64;     // 16 one-wave blocks per (b,c)
constexpr int PIN = 20;           // 80B row pitch: 16B-aligned, conflict-optimal b128
constexpr float FS = 44100.0f;
}

__device__ __forceinline__ float rl(float v, int lane) {
  return __int_as_float(__builtin_amdgcn_readlane(__float_as_int(v), lane));
}

// K1: RBJ peaking-EQ coefficients, normalized by a0. cf[(b*K+k)*5 + {b0,b1,b2,a1,a2}]
__global__ void eq_coeffs(const float* __restrict__ fr, const float* __restrict__ gn,
                          const float* __restrict__ qf, float* __restrict__ cf) {
  int i = blockIdx.x * blockDim.x + threadIdx.x;
  if (i >= B * K) return;
  float f = fr[i], g = gn[i], Q = qf[i];
  float A  = powf(10.0f, g * (1.0f / 40.0f));
  float w0 = 6.283185307179586f * f / FS;
  float cw = cosf(w0);
  float al = sinf(w0) / (2.0f * Q);
  float b0 = 1.0f + al * A;
  float b1 = -2.0f * cw;
  float b2 = 1.0f - al * A;
  float a0 = 1.0f + al / A;
  float a2 = 1.0f - al / A;
  float ia = 1.0f / a0;
  float* p = cf + i * 5;
  p[0] = b0 * ia; p[1] = b1 * ia; p[2] = b2 * ia; p[3] = b1 * ia; p[4] = a2 * ia;
}

// Segment pass, 1 wave per block, LDS transpose-staged I/O (b128 path),
// depth-2 register prefetch. WRITE_OUT=false: zero-state run, record final
// state. WRITE_OUT=true: run from exact incoming state, write output.
template <bool WRITE_OUT>
__global__ __launch_bounds__(64, 1) void eq_pass(const float* __restrict__ x,
                                                 const float* __restrict__ cf,
                                                 const float* __restrict__ st_in,
                                                 float* __restrict__ st_out,
                                                 float* __restrict__ y) {
  __shared__ __align__(16) float sIn[2][64][PIN];
  __shared__ __align__(16) float sOut[WRITE_OUT ? 2 : 1][WRITE_OUT ? 64 : 1][WRITE_OUT ? PIN : 1];

  int l = threadIdx.x;
  int wid = blockIdx.x;           // 0 .. NBC*WPB-1
  int bc = wid / WPB;
  int segbase = (wid % WPB) * 64;
  int b = bc / C;
  int tid = bc * SEG + segbase + l;

  const float4* xp4 = reinterpret_cast<const float4*>(x + (size_t)bc * T + (size_t)segbase * L);
  float4* yp4 = reinterpret_cast<float4*>(y + (size_t)bc * T + (size_t)segbase * L);
  constexpr int Q4 = L / 4;  // 64 float4 per segment

  int sj = l >> 2;   // staging sub-segment 0..15
  int qj = l & 3;    // 16B quarter of the 64B line

  // prologue loads first (hide cf/state loads under them)
  float4 ra[4], rb[4];
#pragma unroll
  for (int j = 0; j < 4; ++j) ra[j] = xp4[(size_t)(j * 16 + sj) * Q4 + qj];
#pragma unroll
  for (int j = 0; j < 4; ++j) rb[j] = xp4[(size_t)(j * 16 + sj) * Q4 + 4 + qj];

  float b0[K], b1c[K], b2c[K], a1c[K], a2c[K];
#pragma unroll
  for (int k = 0; k < K; ++k) {
    const float* p = cf + (b * K + k) * 5;
    b0[k] = p[0]; b1c[k] = p[1]; b2c[k] = p[2]; a1c[k] = p[3]; a2c[k] = p[4];
  }

  float s1[K], s2[K];
  if (WRITE_OUT) {
    const float4* si = reinterpret_cast<const float4*>(st_in + (size_t)tid * NST);
    float4 v0 = si[0], v1 = si[1], v2 = si[2];
    s1[0] = v0.x; s2[0] = v0.y; s1[1] = v0.z; s2[1] = v0.w;
    s1[2] = v1.x; s2[2] = v1.y; s1[3] = v1.z; s2[3] = v1.w;
    s1[4] = v2.x; s2[4] = v2.y; s1[5] = v2.z; s2[5] = v2.w;
  } else {
#pragma unroll
    for (int k = 0; k < K; ++k) { s1[k] = 0.0f; s2[k] = 0.0f; }
  }

  auto tile = [&](float4 (&r)[4], int t, int pb) {
    // stage tile t (regs -> LDS, transposed, b128 writes)
#pragma unroll
    for (int j = 0; j < 4; ++j) {
      int seg = j * 16 + sj;
      *reinterpret_cast<float4*>(&sIn[pb][seg][qj * 4]) = r[j];
    }
    // issue loads for tile t+2 (land during ~2 tiles of compute)
    if (t + 2 < NT) {
#pragma unroll
      for (int j = 0; j < 4; ++j)
        r[j] = xp4[(size_t)(j * 16 + sj) * Q4 + (size_t)(t + 2) * 4 + qj];
    }
    // own segment: 16 sequential samples, inputs via 4 b128 reads
    float4 v0 = *reinterpret_cast<const float4*>(&sIn[pb][l][0]);
    float4 v1 = *reinterpret_cast<const float4*>(&sIn[pb][l][4]);
    float4 v2 = *reinterpret_cast<const float4*>(&sIn[pb][l][8]);
    float4 v3 = *reinterpret_cast<const float4*>(&sIn[pb][l][12]);
    float xs[TS] = {v0.x, v0.y, v0.z, v0.w, v1.x, v1.y, v1.z, v1.w,
                    v2.x, v2.y, v2.z, v2.w, v3.x, v3.y, v3.z, v3.w};
    float out16[TS];
#pragma unroll
    for (int i = 0; i < TS; ++i) {
      float yv = xs[i];
#pragma unroll
      for (int k = 0; k < K; ++k) {
        float yk = fmaf(b0[k], yv, s1[k]);
        float t1 = fmaf(b1c[k], yv, s2[k]);
        s1[k] = fmaf(-a1c[k], yk, t1);
        float t2 = b2c[k] * yv;
        s2[k] = fmaf(-a2c[k], yk, t2);
        yv = yk;
      }
      out16[i] = yv;
    }
    if (WRITE_OUT) {
      // stage outputs (b128 writes), flush as full 64B lines (b128 reads)
      *reinterpret_cast<float4*>(&sOut[pb][l][0])  = make_float4(out16[0], out16[1], out16[2], out16[3]);
      *reinterpret_cast<float4*>(&sOut[pb][l][4])  = make_float4(out16[4], out16[5], out16[6], out16[7]);
      *reinterpret_cast<float4*>(&sOut[pb][l][8])  = make_float4(out16[8], out16[9], out16[10], out16[11]);
      *reinterpret_cast<float4*>(&sOut[pb][l][12]) = make_float4(out16[12], out16[13], out16[14], out16[15]);
#pragma unroll
      for (int j = 0; j < 4; ++j) {
        int seg = j * 16 + sj;
        float4 o = *reinterpret_cast<const float4*>(&sOut[pb][seg][qj * 4]);
        yp4[(size_t)seg * Q4 + (size_t)t * 4 + qj] = o;
      }
    }
  };

  for (int tt = 0; tt < NT; tt += 2) {
    tile(ra, tt, 0);
    tile(rb, tt + 1, 1);
  }

  if (!WRITE_OUT) {
    float4* so = reinterpret_cast<float4*>(st_out + (size_t)tid * NST);
    so[0] = make_float4(s1[0], s2[0], s1[1], s2[1]);
    so[1] = make_float4(s1[2], s2[2], s1[3], s2[3]);
    so[2] = make_float4(s1[4], s2[4], s1[5], s2[5]);
  }
}

// K3: 3-level scan (R4-identical). Phase A: squarings give Phi=A^L (LDS) and
// Phi^GP (row form). Phase B: each lane accumulates its GP-segment group's
// zero-state final with Phi replicated in VGPRs. Phase C: 64-step serial scan
// over groups. Phase D: parallel replay writes per-segment incoming states.
__global__ __launch_bounds__(64, 1) void eq_scan(const float* __restrict__ cf,
                                                 const float* __restrict__ zsf,
                                                 float* __restrict__ sif) {
  __shared__ float PhiL[NST][NST];      // Phi = A^L, [row][col]
  __shared__ float Mx[NST][NST + 1];    // transpose scratch for Phi^GP
  __shared__ float W[64][NST + 1];      // per-group zero-state finals
  __shared__ float SL[64][NST + 1];     // per-group incoming states

  int bc = blockIdx.x;
  int b = bc / C;
  int l = threadIdx.x;
  bool act = (l < NST);

  float b0[K], b1c[K], b2c[K], a1c[K], a2c[K];
#pragma unroll
  for (int k = 0; k < K; ++k) {
    const float* p = cf + (b * K + k) * 5;
    b0[k] = p[0]; b1c[k] = p[1]; b2c[k] = p[2]; a1c[k] = p[3]; a2c[k] = p[4];
  }

  // column l of the one-sample homogeneous map A
  float col[NST];
  {
    float s1[K], s2[K];
#pragma unroll
    for (int k = 0; k < K; ++k) {
      s1[k] = (l == 2 * k) ? 1.0f : 0.0f;
      s2[k] = (l == 2 * k + 1) ? 1.0f : 0.0f;
    }
    float yv = 0.0f;
#pragma unroll
    for (int k = 0; k < K; ++k) {
      float yk = fmaf(b0[k], yv, s1[k]);
      float t1 = fmaf(b1c[k], yv, s2[k]);
      float ns1 = fmaf(-a1c[k], yk, t1);
      float ns2 = fmaf(-a2c[k], yk, b2c[k] * yv);
      s1[k] = ns1; s2[k] = ns2; yv = yk;
    }
#pragma unroll
    for (int k = 0; k < K; ++k) { col[2 * k] = s1[k]; col[2 * k + 1] = s2[k]; }
  }

  auto square = [&]() {
    float nc[NST];
#pragma unroll
    for (int r = 0; r < NST; ++r) nc[r] = 0.0f;
#pragma unroll
    for (int m = 0; m < NST; ++m) {
      float wv = col[m];
#pragma unroll
      for (int r = 0; r < NST; ++r) nc[r] = fmaf(rl(col[r], m), wv, nc[r]);
    }
#pragma unroll
    for (int r = 0; r < NST; ++r) col[r] = nc[r];
  };

  for (int p = 0; p < LOG2L; ++p) square();          // Phi = A^L
  if (act) {
#pragma unroll
    for (int r = 0; r < NST; ++r) PhiL[r][l] = col[r];
  }
  __syncthreads();

  for (int p = 0; p < 4; ++p) square();              // Phi_g = A^(GP*L)
  if (act) {
#pragma unroll
    for (int r = 0; r < NST; ++r) Mx[r][l] = col[r];
  }
  __syncthreads();
  float row[NST];
#pragma unroll
  for (int m = 0; m < NST; ++m) row[m] = act ? Mx[l][m] : 0.0f;

  // replicate Phi into every lane's registers (broadcast LDS reads)
  float phi[NST][NST];
#pragma unroll
  for (int r = 0; r < NST; ++r)
#pragma unroll
    for (int m = 0; m < NST; ++m) phi[r][m] = PhiL[r][m];

  // Phase B: lane g accumulates zero-state final over its GP segments
  const float* zb = zsf + ((size_t)bc * SEG + (size_t)l * GP) * NST;
  float s[NST];
#pragma unroll
  for (int r = 0; r < NST; ++r) s[r] = 0.0f;
  {
    float zc[NST], zn[NST];
    const float4* zp = reinterpret_cast<const float4*>(zb);
    float4 v0 = zp[0], v1 = zp[1], v2 = zp[2];
    zc[0] = v0.x; zc[1] = v0.y; zc[2] = v0.z; zc[3] = v0.w;
    zc[4] = v1.x; zc[5] = v1.y; zc[6] = v1.z; zc[7] = v1.w;
    zc[8] = v2.x; zc[9] = v2.y; zc[10] = v2.z; zc[11] = v2.w;
    for (int j = 0; j < GP; ++j) {
      if (j + 1 < GP) {
        const float4* zq = reinterpret_cast<const float4*>(zb + (size_t)(j + 1) * NST);
        float4 w0 = zq[0], w1 = zq[1], w2 = zq[2];
        zn[0] = w0.x; zn[1] = w0.y; zn[2] = w0.z; zn[3] = w0.w;
        zn[4] = w1.x; zn[5] = w1.y; zn[6] = w1.z; zn[7] = w1.w;
        zn[8] = w2.x; zn[9] = w2.y; zn[10] = w2.z; zn[11] = w2.w;
      }
      float ns[NST];
#pragma unroll
      for (int r = 0; r < NST; ++r) {
        float a = zc[r];
#pragma unroll
        for (int m = 0; m < NST; ++m) a = fmaf(phi[r][m], s[m], a);
        ns[r] = a;
      }
#pragma unroll
      for (int r = 0; r < NST; ++r) s[r] = ns[r];
#pragma unroll
      for (int r = 0; r < NST; ++r) zc[r] = zn[r];
    }
  }
#pragma unroll
  for (int r = 0; r < NST; ++r) W[l][r] = s[r];
  __syncthreads();

  // Phase C: 64-step serial scan over groups; lane r carries component r
  {
    float sv = 0.0f;
    for (int i = 0; i < 64; ++i) {
      if (act) SL[i][l] = sv;          // incoming state of group i
      float wv = act ? W[i][l] : 0.0f;
      float t0 = fmaf(row[0], rl(sv, 0), fmaf(row[1], rl(sv, 1), row[2] * rl(sv, 2)));
      float t1 = fmaf(row[3], rl(sv, 3), fmaf(row[4], rl(sv, 4), row[5] * rl(sv, 5)));
      float t2 = fmaf(row[6], rl(sv, 6), fmaf(row[7], rl(sv, 7), row[8] * rl(sv, 8)));
      float t3 = fmaf(row[9], rl(sv, 9), fmaf(row[10], rl(sv, 10), row[11] * rl(sv, 11)));
      sv = ((t0 + t1) + (t2 + t3)) + wv;
    }
  }
  __syncthreads();

  // Phase D: replay — lane g emits incoming state of each of its segments
  float sg[NST];
#pragma unroll
  for (int r = 0; r < NST; ++r) sg[r] = SL[l][r];
  {
    float zc[NST], zn[NST];
    const float4* zp = reinterpret_cast<const float4*>(zb);
    float4 v0 = zp[0], v1 = zp[1], v2 = zp[2];
    zc[0] = v0.x; zc[1] = v0.y; zc[2] = v0.z; zc[3] = v0.w;
    zc[4] = v1.x; zc[5] = v1.y; zc[6] = v1.z; zc[7] = v1.w;
    zc[8] = v2.x; zc[9] = v2.y; zc[10] = v2.z; zc[11] = v2.w;
    float* ob = sif + ((size_t)bc * SEG + (size_t)l * GP) * NST;
    for (int j = 0; j < GP; ++j) {
      if (j + 1 < GP) {
        const float4* zq = reinterpret_cast<const float4*>(zb + (size_t)(j + 1) * NST);
        float4 w0 = zq[0], w1 = zq[1], w2 = zq[2];
        zn[0] = w0.x; zn[1] = w0.y; zn[2] = w0.z; zn[3] = w0.w;
        zn[4] = w1.x; zn[5] = w1.y; zn[6] = w1.z; zn[7] = w1.w;
        zn[8] = w2.x; zn[9] = w2.y; zn[10] = w2.z; zn[11] = w2.w;
      }
      float4* op = reinterpret_cast<float4*>(ob + (size_t)j * NST);
      op[0] = make_float4(sg[0], sg[1], sg[2], sg[3]);
      op[1] = make_float4(sg[4], sg[5], sg[6], sg[7]);
      op[2] = make_float4(sg[8], sg[9], sg[10], sg[11]);
      float ns[NST];
#pragma unroll
      for (int r = 0; r < NST; ++r) {
        float a = zc[r];
#pragma unroll
        for (int m = 0; m < NST; ++m) a = fmaf(phi[r][m], sg[m], a);
        ns[r] = a;
      }
#pragma unroll
      for (int r = 0; r < NST; ++r) sg[r] = ns[r];
#pragma unroll
      for (int r = 0; r < NST; ++r) zc[r] = zn[r];
    }
  }
}

extern "C" void kernel_launch(void* const* d_in, const int* in_sizes, int n_in,
                              void* d_out, int out_size, void* d_ws, size_t ws_size,
                              hipStream_t stream) {
  const float* audio = (const float*)d_in[0];
  const float* fr    = (const float*)d_in[1];
  const float* gn    = (const float*)d_in[2];
  const float* qf    = (const float*)d_in[3];
  float* out = (float*)d_out;

  // ws layout (floats): coeffs | zero-state finals | incoming states
  float* cf  = (float*)d_ws;                    // B*K*5 = 960
  float* zsf = cf + B * K * 5;                  // NBC*SEG*NST = 786432
  float* sif = zsf + (size_t)NBC * SEG * NST;   // 786432

  hipLaunchKernelGGL(eq_coeffs, dim3((B * K + 63) / 64), dim3(64), 0, stream,
                     fr, gn, qf, cf);
  hipLaunchKernelGGL((eq_pass<false>), dim3(NBC * WPB), dim3(64), 0, stream,
                     audio, cf, nullptr, zsf, out);
  hipLaunchKernelGGL(eq_scan, dim3(NBC), dim3(64), 0, stream, cf, zsf, sif);
  hipLaunchKernelGGL((eq_pass<true>), dim3(NBC * WPB), dim3(64), 0, stream,
                     audio, cf, sif, nullptr, out);
}

// Round 12
// 91.593 us; speedup vs baseline: 1.1120x; 1.1120x over previous
//
#include <hip/hip_runtime.h>
#include <math.h>

namespace {
constexpr int B = 32, C = 2, T = 262144, K = 6;
constexpr int SEG = 2048;         // segments per (b,c)
constexpr int L = T / SEG;        // 128 samples per segment
constexpr int NBC = B * C;        // 64 sequences
constexpr int NST = 2 * K;        // 12-dim cascade state
constexpr int LOG2L = 7;          // L = 2^7
constexpr int RPB = 128;          // rows (segments) per block: 64 lanes x 2
constexpr int WPB = SEG / RPB;    // 16 one-wave blocks per (b,c)
constexpr int TS = 16;            // samples per staging tile
constexpr int NT = L / TS;        // 8 tiles
constexpr int Q4 = L / 4;         // 32 float4 per segment
constexpr int PIN = 17;           // scalar pitch, 2 lanes/bank = conflict-free
constexpr int GP = 8;             // segments per scan thread
constexpr int NW = 4;             // scan waves per block (256 threads)
constexpr float FS = 44100.0f;
}

__device__ __forceinline__ float rl(float v, int lane) {
  return __int_as_float(__builtin_amdgcn_readlane(__float_as_int(v), lane));
}

__device__ __forceinline__ void ld12(const float* p, float (&v)[NST]) {
  const float4* q = reinterpret_cast<const float4*>(p);
  float4 a = q[0], b4 = q[1], c4 = q[2];
  v[0] = a.x; v[1] = a.y; v[2] = a.z; v[3] = a.w;
  v[4] = b4.x; v[5] = b4.y; v[6] = b4.z; v[7] = b4.w;
  v[8] = c4.x; v[9] = c4.y; v[10] = c4.z; v[11] = c4.w;
}

__device__ __forceinline__ void st12(float* p, const float (&v)[NST]) {
  float4* q = reinterpret_cast<float4*>(p);
  q[0] = make_float4(v[0], v[1], v[2], v[3]);
  q[1] = make_float4(v[4], v[5], v[6], v[7]);
  q[2] = make_float4(v[8], v[9], v[10], v[11]);
}

// s = M*s + z (12x12 affine step, fully register-resident)
__device__ __forceinline__ void affine(const float (&M)[NST][NST], float (&s)[NST],
                                       const float (&z)[NST]) {
  float ns[NST];
#pragma unroll
  for (int r = 0; r < NST; ++r) {
    float a = z[r];
#pragma unroll
    for (int m = 0; m < NST; ++m) a = fmaf(M[r][m], s[m], a);
    ns[r] = a;
  }
#pragma unroll
  for (int r = 0; r < NST; ++r) s[r] = ns[r];
}

// K1: RBJ peaking-EQ coefficients, normalized by a0.
__global__ void eq_coeffs(const float* __restrict__ fr, const float* __restrict__ gn,
                          const float* __restrict__ qf, float* __restrict__ cf) {
  int i = blockIdx.x * blockDim.x + threadIdx.x;
  if (i >= B * K) return;
  float f = fr[i], g = gn[i], Q = qf[i];
  float A  = powf(10.0f, g * (1.0f / 40.0f));
  float w0 = 6.283185307179586f * f / FS;
  float cw = cosf(w0);
  float al = sinf(w0) / (2.0f * Q);
  float b0 = 1.0f + al * A;
  float b1 = -2.0f * cw;
  float b2 = 1.0f - al * A;
  float a0 = 1.0f + al / A;
  float a2 = 1.0f - al / A;
  float ia = 1.0f / a0;
  float* p = cf + i * 5;
  p[0] = b0 * ia; p[1] = b1 * ia; p[2] = b2 * ia; p[3] = b1 * ia; p[4] = a2 * ia;
}

// Segment pass, 1 wave per block, ILP2: lane l owns segments l and l+64 of a
// 128-row block. Single-buffer LDS (wave-synchronous), scalar [17] staging,
// depth-1 prefetch of 8 float4.
template <bool WRITE_OUT>
__global__ __launch_bounds__(64, 1) void eq_pass(const float* __restrict__ x,
                                                 const float* __restrict__ cf,
                                                 const float* __restrict__ st_in,
                                                 float* __restrict__ st_out,
                                                 float* __restrict__ y) {
  __shared__ float sIn[RPB][PIN];                                   // 8704 B
  __shared__ float sOut[WRITE_OUT ? RPB : 1][WRITE_OUT ? PIN : 1];  // 8704 B (passB)

  int l = threadIdx.x;
  int wid = blockIdx.x;            // 0 .. NBC*WPB-1
  int bc = wid / WPB;
  int segbase = (wid % WPB) * RPB;
  int b = bc / C;
  int tidA = bc * SEG + segbase + l;
  int tidB = tidA + 64;

  const float4* xp4 = reinterpret_cast<const float4*>(x + (size_t)bc * T + (size_t)segbase * L);
  float4* yp4 = reinterpret_cast<float4*>(y + (size_t)bc * T + (size_t)segbase * L);

  int sj = l >> 2;   // staging sub-segment 0..15
  int qj = l & 3;    // 16B quarter of the 64B line

  // prologue: tile 0 loads first (hide cf/state loads under them)
  float4 r[8];
#pragma unroll
  for (int j = 0; j < 8; ++j) r[j] = xp4[(size_t)(j * 16 + sj) * Q4 + qj];

  float b0[K], b1c[K], b2c[K], a1c[K], a2c[K];
#pragma unroll
  for (int k = 0; k < K; ++k) {
    const float* p = cf + (b * K + k) * 5;
    b0[k] = p[0]; b1c[k] = p[1]; b2c[k] = p[2]; a1c[k] = p[3]; a2c[k] = p[4];
  }

  float s1a[K], s2a[K], s1b[K], s2b[K];
  if (WRITE_OUT) {
    float st[NST];
    ld12(st_in + (size_t)tidA * NST, st);
#pragma unroll
    for (int k = 0; k < K; ++k) { s1a[k] = st[2 * k]; s2a[k] = st[2 * k + 1]; }
    ld12(st_in + (size_t)tidB * NST, st);
#pragma unroll
    for (int k = 0; k < K; ++k) { s1b[k] = st[2 * k]; s2b[k] = st[2 * k + 1]; }
  } else {
#pragma unroll
    for (int k = 0; k < K; ++k) { s1a[k] = 0.0f; s2a[k] = 0.0f; s1b[k] = 0.0f; s2b[k] = 0.0f; }
  }

  for (int t = 0; t < NT; ++t) {
    // stage tile t (regs -> LDS, transposed; ~2 lanes/bank per instr = free)
#pragma unroll
    for (int j = 0; j < 8; ++j) {
      int row = j * 16 + sj;
      sIn[row][qj * 4 + 0] = r[j].x;
      sIn[row][qj * 4 + 1] = r[j].y;
      sIn[row][qj * 4 + 2] = r[j].z;
      sIn[row][qj * 4 + 3] = r[j].w;
    }
    // issue loads for tile t+1 (land during this tile's ~2k cyc of compute)
    if (t + 1 < NT) {
#pragma unroll
      for (int j = 0; j < 8; ++j)
        r[j] = xp4[(size_t)(j * 16 + sj) * Q4 + (size_t)(t + 1) * 4 + qj];
    }
    // read both owned rows (scalar, conflict-free)
    float xa[TS], xb[TS];
#pragma unroll
    for (int i = 0; i < TS; ++i) { xa[i] = sIn[l][i]; xb[i] = sIn[64 + l][i]; }
    // two independent cascades, interleaved for ILP
#pragma unroll
    for (int i = 0; i < TS; ++i) {
      float ya = xa[i], yb = xb[i];
#pragma unroll
      for (int k = 0; k < K; ++k) {
        float yka = fmaf(b0[k], ya, s1a[k]);
        float ykb = fmaf(b0[k], yb, s1b[k]);
        float t1a = fmaf(b1c[k], ya, s2a[k]);
        float t1b = fmaf(b1c[k], yb, s2b[k]);
        s1a[k] = fmaf(-a1c[k], yka, t1a);
        s1b[k] = fmaf(-a1c[k], ykb, t1b);
        float t2a = b2c[k] * ya;
        float t2b = b2c[k] * yb;
        s2a[k] = fmaf(-a2c[k], yka, t2a);
        s2b[k] = fmaf(-a2c[k], ykb, t2b);
        ya = yka; yb = ykb;
      }
      if (WRITE_OUT) { sOut[l][i] = ya; sOut[64 + l][i] = yb; }
    }
    if (WRITE_OUT) {
      // flush as full 64B lines (gather from LDS, in-order per wave)
#pragma unroll
      for (int j = 0; j < 8; ++j) {
        int row = j * 16 + sj;
        float4 o;
        o.x = sOut[row][qj * 4 + 0];
        o.y = sOut[row][qj * 4 + 1];
        o.z = sOut[row][qj * 4 + 2];
        o.w = sOut[row][qj * 4 + 3];
        yp4[(size_t)row * Q4 + (size_t)t * 4 + qj] = o;
      }
    }
  }

  if (!WRITE_OUT) {
    float st[NST];
#pragma unroll
    for (int k = 0; k < K; ++k) { st[2 * k] = s1a[k]; st[2 * k + 1] = s2a[k]; }
    st12(st_out + (size_t)tidA * NST, st);
#pragma unroll
    for (int k = 0; k < K; ++k) { st[2 * k] = s1b[k]; st[2 * k + 1] = s2b[k]; }
    st12(st_out + (size_t)tidB * NST, st);
  }
}

// K3: hierarchical scan, 256 threads (4 waves) per (b,c). (R10 verbatim)
__global__ __launch_bounds__(256, 1) void eq_scan(const float* __restrict__ cf,
                                                  const float* __restrict__ zsf,
                                                  float* __restrict__ sif) {
  __shared__ float PhiL[NST][NST];
  __shared__ float Rg[NST][NST + 1];
  __shared__ float Rw[NST][NST + 1];
  __shared__ float FB[NW][64][NST + 1];
  __shared__ float SL[NW][64][NST + 1];
  __shared__ float WF[NW][NST + 1];

  int bc = blockIdx.x;
  int b = bc / C;
  int t = threadIdx.x;
  int w = t >> 6;
  int l = t & 63;
  bool act = (l < NST);

  float b0[K], b1c[K], b2c[K], a1c[K], a2c[K];
#pragma unroll
  for (int k = 0; k < K; ++k) {
    const float* p = cf + (b * K + k) * 5;
    b0[k] = p[0]; b1c[k] = p[1]; b2c[k] = p[2]; a1c[k] = p[3]; a2c[k] = p[4];
  }

  // column l of the one-sample homogeneous map A
  float col[NST];
  {
    float s1[K], s2[K];
#pragma unroll
    for (int k = 0; k < K; ++k) {
      s1[k] = (l == 2 * k) ? 1.0f : 0.0f;
      s2[k] = (l == 2 * k + 1) ? 1.0f : 0.0f;
    }
    float yv = 0.0f;
#pragma unroll
    for (int k = 0; k < K; ++k) {
      float yk = fmaf(b0[k], yv, s1[k]);
      float t1 = fmaf(b1c[k], yv, s2[k]);
      float ns1 = fmaf(-a1c[k], yk, t1);
      float ns2 = fmaf(-a2c[k], yk, b2c[k] * yv);
      s1[k] = ns1; s2[k] = ns2; yv = yk;
    }
#pragma unroll
    for (int k = 0; k < K; ++k) { col[2 * k] = s1[k]; col[2 * k + 1] = s2[k]; }
  }

  auto square = [&]() {
    float nc[NST];
#pragma unroll
    for (int r = 0; r < NST; ++r) nc[r] = 0.0f;
#pragma unroll
    for (int m = 0; m < NST; ++m) {
      float wv = col[m];
#pragma unroll
      for (int r = 0; r < NST; ++r) nc[r] = fmaf(rl(col[r], m), wv, nc[r]);
    }
#pragma unroll
    for (int r = 0; r < NST; ++r) col[r] = nc[r];
  };

  for (int p = 0; p < LOG2L; ++p) square();          // Phi = A^128
  if (w == 0 && act) {
#pragma unroll
    for (int r = 0; r < NST; ++r) PhiL[r][l] = col[r];
  }
  for (int p = 0; p < 3; ++p) square();              // Phi_g = A^1024
  if (w == 0 && act) {
#pragma unroll
    for (int r = 0; r < NST; ++r) Rg[r][l] = col[r];
  }
  for (int p = 0; p < 6; ++p) square();              // Phi_w = A^65536
  if (w == 0 && act) {
#pragma unroll
    for (int r = 0; r < NST; ++r) Rw[r][l] = col[r];
  }
  __syncthreads();

  float rowg[NST], roww[NST];
#pragma unroll
  for (int m = 0; m < NST; ++m) {
    rowg[m] = act ? Rg[l][m] : 0.0f;
    roww[m] = act ? Rw[l][m] : 0.0f;
  }
  float phi[NST][NST];
#pragma unroll
  for (int r = 0; r < NST; ++r)
#pragma unroll
    for (int m = 0; m < NST; ++m) phi[r][m] = PhiL[r][m];

  // Phase B: zero-incoming final over this thread's GP segments
  const float* zb = zsf + ((size_t)bc * SEG + (size_t)t * GP) * NST;
  float s[NST];
  ld12(zb, s);
#pragma unroll
  for (int j = 1; j < GP; ++j) {
    float zc[NST];
    ld12(zb + (size_t)j * NST, zc);
    affine(phi, s, zc);
  }
#pragma unroll
  for (int r = 0; r < NST; ++r) FB[w][l][r] = s[r];
  __syncthreads();

  // C1a: wave serial scan (zero incoming) -> wave final
  {
    float sv = 0.0f;
    for (int i = 0; i < 64; ++i) {
      float wv = act ? FB[w][i][l] : 0.0f;
      float t0 = fmaf(rowg[0], rl(sv, 0), fmaf(rowg[1], rl(sv, 1), rowg[2] * rl(sv, 2)));
      float t1 = fmaf(rowg[3], rl(sv, 3), fmaf(rowg[4], rl(sv, 4), rowg[5] * rl(sv, 5)));
      float t2 = fmaf(rowg[6], rl(sv, 6), fmaf(rowg[7], rl(sv, 7), rowg[8] * rl(sv, 8)));
      float t3 = fmaf(rowg[9], rl(sv, 9), fmaf(rowg[10], rl(sv, 10), rowg[11] * rl(sv, 11)));
      sv = ((t0 + t1) + (t2 + t3)) + wv;
    }
    if (act) WF[w][l] = sv;
  }
  __syncthreads();

  // C2: block scan over wave finals (wave w folds w steps)
  float swv = 0.0f;
  for (int w2 = 0; w2 < w; ++w2) {
    float wfv = act ? WF[w2][l] : 0.0f;
    float t0 = fmaf(roww[0], rl(swv, 0), fmaf(roww[1], rl(swv, 1), roww[2] * rl(swv, 2)));
    float t1 = fmaf(roww[3], rl(swv, 3), fmaf(roww[4], rl(swv, 4), roww[5] * rl(swv, 5)));
    float t2 = fmaf(roww[6], rl(swv, 6), fmaf(roww[7], rl(swv, 7), roww[8] * rl(swv, 8)));
    float t3 = fmaf(roww[9], rl(swv, 9), fmaf(roww[10], rl(swv, 10), roww[11] * rl(swv, 11)));
    swv = ((t0 + t1) + (t2 + t3)) + wfv;
  }

  // C1b: re-scan from true wave incoming; store per-group incoming states
  {
    float sv = swv;
    for (int i = 0; i < 64; ++i) {
      if (act) SL[w][i][l] = sv;
      float wv = act ? FB[w][i][l] : 0.0f;
      float t0 = fmaf(rowg[0], rl(sv, 0), fmaf(rowg[1], rl(sv, 1), rowg[2] * rl(sv, 2)));
      float t1 = fmaf(rowg[3], rl(sv, 3), fmaf(rowg[4], rl(sv, 4), rowg[5] * rl(sv, 5)));
      float t2 = fmaf(rowg[6], rl(sv, 6), fmaf(rowg[7], rl(sv, 7), rowg[8] * rl(sv, 8)));
      float t3 = fmaf(rowg[9], rl(sv, 9), fmaf(rowg[10], rl(sv, 10), rowg[11] * rl(sv, 11)));
      sv = ((t0 + t1) + (t2 + t3)) + wv;
    }
  }
  __syncthreads();

  // Phase D: replay — emit incoming state of each owned segment
  float sg[NST];
#pragma unroll
  for (int r = 0; r < NST; ++r) sg[r] = SL[w][l][r];
  float* ob = sif + ((size_t)bc * SEG + (size_t)t * GP) * NST;
#pragma unroll
  for (int j = 0; j < GP; ++j) {
    st12(ob + (size_t)j * NST, sg);
    if (j + 1 < GP) {
      float zc[NST];
      ld12(zb + (size_t)j * NST, zc);
      affine(phi, sg, zc);
    }
  }
}

extern "C" void kernel_launch(void* const* d_in, const int* in_sizes, int n_in,
                              void* d_out, int out_size, void* d_ws, size_t ws_size,
                              hipStream_t stream) {
  const float* audio = (const float*)d_in[0];
  const float* fr    = (const float*)d_in[1];
  const float* gn    = (const float*)d_in[2];
  const float* qf    = (const float*)d_in[3];
  float* out = (float*)d_out;

  // ws layout (floats): coeffs | zero-state finals | incoming states
  float* cf  = (float*)d_ws;                    // B*K*5 = 960
  float* zsf = cf + B * K * 5;                  // NBC*SEG*NST = 1572864
  float* sif = zsf + (size_t)NBC * SEG * NST;   // 1572864

  hipLaunchKernelGGL(eq_coeffs, dim3((B * K + 63) / 64), dim3(64), 0, stream,
                     fr, gn, qf, cf);
  hipLaunchKernelGGL((eq_pass<false>), dim3(NBC * WPB), dim3(64), 0, stream,
                     audio, cf, nullptr, zsf, out);
  hipLaunchKernelGGL(eq_scan, dim3(NBC), dim3(256), 0, stream, cf, zsf, sif);
  hipLaunchKernelGGL((eq_pass<true>), dim3(NBC * WPB), dim3(64), 0, stream,
                     audio, cf, sif, nullptr, out);
}